// Round 5
// baseline (89.972 us; speedup 1.0000x reference)
//
#include <hip/hip_runtime.h>

#define IO_DIM 64
#define WIDTH 16
#define HID 128
#define BS_ 1024                 // 64*16
#define NTHREADS 256

// ws layout v2 (floats):
//   wT [64][16]  at    0..1024)   : wT[k][j] = w[j][k]
//   uT [64][16]  at 1024..2048)   : uT[d][j] = u[j][d] / 16
//   bb [16]      at 2048..2064)
//   nuw[16]      at 2064..2080)   : -uw[j] / 16

__device__ __forceinline__ float fast_tanh(float x) {
    float e = __expf(2.0f * x);
    return 1.0f - __fdividef(2.0f, e + 1.0f);
}

__global__ __launch_bounds__(128) void cnf_prep(
    const float* __restrict__ t, const float* __restrict__ W1,
    const float* __restrict__ b1, const float* __restrict__ W2,
    const float* __restrict__ b2, const float* __restrict__ W3,
    const float* __restrict__ b3, float* __restrict__ ws)
{
    __shared__ float h1[HID];
    __shared__ float h2[HID];
    __shared__ float su[64], sw[64];
    const int tid = threadIdx.x;

    h1[tid] = tanhf(W1[tid] * t[0] + b1[tid]);
    __syncthreads();

    {
        float s = b2[tid];
        const float4* W2v = (const float4*)(W2 + tid * HID);
        #pragma unroll 8
        for (int k = 0; k < HID / 4; ++k) {
            float4 wv = W2v[k];
            s = fmaf(wv.x, h1[4 * k + 0], s);
            s = fmaf(wv.y, h1[4 * k + 1], s);
            s = fmaf(wv.z, h1[4 * k + 2], s);
            s = fmaf(wv.w, h1[4 * k + 3], s);
        }
        h2[tid] = tanhf(s);
    }
    __syncthreads();

    const int b = blockIdx.x;
    if (b < 16) {
        // block b owns output row j=b of both u and w (64 elements each)
        const int half = tid >> 6;   // 0 -> u, 1 -> w
        const int i = tid & 63;      // element index (d or k)
        const int row = half * BS_ + b * 64 + i;
        float s = b3[row];
        const float4* W3v = (const float4*)(W3 + row * HID);
        #pragma unroll 8
        for (int k = 0; k < HID / 4; ++k) {
            float4 wv = W3v[k];
            s = fmaf(wv.x, h2[4 * k + 0], s);
            s = fmaf(wv.y, h2[4 * k + 1], s);
            s = fmaf(wv.z, h2[4 * k + 2], s);
            s = fmaf(wv.w, h2[4 * k + 3], s);
        }
        if (half == 0) {
            ws[1024 + i * 16 + b] = s * (1.0f / WIDTH);   // uT[d][j], scale folded
            su[i] = s;
        } else {
            ws[i * 16 + b] = s;                           // wT[k][j]
            sw[i] = s;
        }
        __syncthreads();
        if (tid < 64) {
            float p = su[tid] * sw[tid];
            #pragma unroll
            for (int m = 32; m >= 1; m >>= 1) p += __shfl_xor(p, m, 64);
            if (tid == 0) ws[2064 + b] = -p * (1.0f / WIDTH);   // nuw[b]
        }
    } else {
        if (tid < WIDTH) {
            const int row = 2 * BS_ + tid;
            float s = b3[row];
            const float4* W3v = (const float4*)(W3 + row * HID);
            #pragma unroll 8
            for (int k = 0; k < HID / 4; ++k) {
                float4 wv = W3v[k];
                s = fmaf(wv.x, h2[4 * k + 0], s);
                s = fmaf(wv.y, h2[4 * k + 1], s);
                s = fmaf(wv.z, h2[4 * k + 2], s);
                s = fmaf(wv.w, h2[4 * k + 3], s);
            }
            ws[2048 + tid] = s;   // bb
        }
    }
}

__global__ __launch_bounds__(NTHREADS, 8) void cnf_main(
    const float* __restrict__ z, const float* __restrict__ ws,
    float* __restrict__ dz, float* __restrict__ dlog, int n)
{
    // wave-private transpose slices: 4 waves x 64 rows x 4 float4 = 16 KB.
    // No __syncthreads anywhere: each wave reads/writes only its own slice,
    // and same-wave DS ops execute in order in the LDS pipe.
    __shared__ __align__(16) float4 wtile[4][64][4];

    const int tid = threadIdx.x;
    const int wv  = tid >> 6;
    const int l   = tid & 63;
    const int base = blockIdx.x * NTHREADS;
    const int row  = base + tid;
    const bool valid = row < n;
    const int lrow = valid ? row : (n - 1);

    const float4* zg = (const float4*)z + (size_t)lrow * 16;

    // phase 1: a[j] = bb[j] + sum_k z[k] * wT[k][j]  (weights via uniform s_load)
    float a[WIDTH];
    #pragma unroll
    for (int j = 0; j < WIDTH; ++j) a[j] = ws[2048 + j];

    #pragma unroll
    for (int kc = 0; kc < 16; ++kc) {
        const float4 zv = zg[kc];
        const float* wk = ws + kc * 64;   // wT rows 4kc..4kc+3
        #pragma unroll
        for (int j = 0; j < WIDTH; ++j) a[j] = fmaf(zv.x, wk[j],      a[j]);
        #pragma unroll
        for (int j = 0; j < WIDTH; ++j) a[j] = fmaf(zv.y, wk[16 + j], a[j]);
        #pragma unroll
        for (int j = 0; j < WIDTH; ++j) a[j] = fmaf(zv.z, wk[32 + j], a[j]);
        #pragma unroll
        for (int j = 0; j < WIDTH; ++j) a[j] = fmaf(zv.w, wk[48 + j], a[j]);
    }

    // tanh + trace
    float tr = 0.0f;
    #pragma unroll
    for (int j = 0; j < WIDTH; ++j) {
        float th = fast_tanh(a[j]);
        a[j] = th;
        tr = fmaf(1.0f - th * th, ws[2064 + j], tr);
    }
    if (valid) dlog[row] = tr;

    // phase 2: dz = th @ uT, 4 passes of 16 cols; wave-private LDS transpose
    const float* uT = ws + 1024;
    float4* dzv = (float4*)dz;

    #pragma unroll
    for (int p = 0; p < 4; ++p) {
        // compute this pass's 4 float4 and write to own slot (XOR-swizzled)
        #pragma unroll
        for (int c = 0; c < 4; ++c) {
            const int d0 = p * 16 + c * 4;
            float4 o = make_float4(0.f, 0.f, 0.f, 0.f);
            #pragma unroll
            for (int j = 0; j < WIDTH; ++j) {
                const float th = a[j];
                o.x = fmaf(th, uT[(d0 + 0) * 16 + j], o.x);
                o.y = fmaf(th, uT[(d0 + 1) * 16 + j], o.y);
                o.z = fmaf(th, uT[(d0 + 2) * 16 + j], o.z);
                o.w = fmaf(th, uT[(d0 + 3) * 16 + j], o.w);
            }
            wtile[wv][l][c ^ (l & 3)] = o;
        }
        // transposed store: 4 instructions, each ~1 KB over 16 rows (64 B/row)
        #pragma unroll
        for (int s = 0; s < 4; ++s) {
            const int idx = s * 64 + l;        // 0..255 within wave's 64 rows
            const int r = idx >> 2, c = idx & 3;
            const float4 v = wtile[wv][r][c ^ (r & 3)];
            const int grow = base + wv * 64 + r;
            if (grow < n)
                dzv[(size_t)grow * 16 + p * 4 + c] = v;
        }
    }
}

extern "C" void kernel_launch(void* const* d_in, const int* in_sizes, int n_in,
                              void* d_out, int out_size, void* d_ws, size_t ws_size,
                              hipStream_t stream) {
    const float* t  = (const float*)d_in[0];
    const float* z  = (const float*)d_in[1];
    const float* W1 = (const float*)d_in[2];
    const float* b1 = (const float*)d_in[3];
    const float* W2 = (const float*)d_in[4];
    const float* b2 = (const float*)d_in[5];
    const float* W3 = (const float*)d_in[6];
    const float* b3 = (const float*)d_in[7];

    const int n = in_sizes[1] / IO_DIM;   // 500000
    float* ws   = (float*)d_ws;
    float* out  = (float*)d_out;
    float* dz   = out;
    float* dlog = out + (size_t)n * IO_DIM;

    cnf_prep<<<17, 128, 0, stream>>>(t, W1, b1, W2, b2, W3, b3, ws);

    const int grid = (n + NTHREADS - 1) / NTHREADS;
    cnf_main<<<grid, NTHREADS, 0, stream>>>(z, ws, dz, dlog, n);
}

// Round 6
// 79.934 us; speedup vs baseline: 1.1256x; 1.1256x over previous
//
#include <hip/hip_runtime.h>

#define IO_DIM 64
#define WIDTH 16
#define HID 128
#define BS_ 1024                 // 64*16
#define NTHREADS 256

// ws layout v2 (floats):
//   wT [64][16]  at    0..1024)   : wT[k][j] = w[j][k]
//   uT [64][16]  at 1024..2048)   : uT[d][j] = u[j][d] / 16
//   bb [16]      at 2048..2064)
//   nuw[16]      at 2064..2080)   : -uw[j] / 16

__device__ __forceinline__ float fast_tanh(float x) {
    float e = __expf(2.0f * x);
    return 1.0f - __fdividef(2.0f, e + 1.0f);
}

__global__ __launch_bounds__(128) void cnf_prep(
    const float* __restrict__ t, const float* __restrict__ W1,
    const float* __restrict__ b1, const float* __restrict__ W2,
    const float* __restrict__ b2, const float* __restrict__ W3,
    const float* __restrict__ b3, float* __restrict__ ws)
{
    __shared__ float h1[HID];
    __shared__ float h2[HID];
    __shared__ float su[64], sw[64];
    const int tid = threadIdx.x;

    h1[tid] = tanhf(W1[tid] * t[0] + b1[tid]);
    __syncthreads();

    {
        float s = b2[tid];
        const float4* W2v = (const float4*)(W2 + tid * HID);
        #pragma unroll 8
        for (int k = 0; k < HID / 4; ++k) {
            float4 wv = W2v[k];
            s = fmaf(wv.x, h1[4 * k + 0], s);
            s = fmaf(wv.y, h1[4 * k + 1], s);
            s = fmaf(wv.z, h1[4 * k + 2], s);
            s = fmaf(wv.w, h1[4 * k + 3], s);
        }
        h2[tid] = tanhf(s);
    }
    __syncthreads();

    const int b = blockIdx.x;
    if (b < 16) {
        // block b owns output row j=b of both u and w (64 elements each)
        const int half = tid >> 6;   // 0 -> u, 1 -> w
        const int i = tid & 63;      // element index (d or k)
        const int row = half * BS_ + b * 64 + i;
        float s = b3[row];
        const float4* W3v = (const float4*)(W3 + row * HID);
        #pragma unroll 8
        for (int k = 0; k < HID / 4; ++k) {
            float4 wv = W3v[k];
            s = fmaf(wv.x, h2[4 * k + 0], s);
            s = fmaf(wv.y, h2[4 * k + 1], s);
            s = fmaf(wv.z, h2[4 * k + 2], s);
            s = fmaf(wv.w, h2[4 * k + 3], s);
        }
        if (half == 0) {
            ws[1024 + i * 16 + b] = s * (1.0f / WIDTH);   // uT[d][j], scale folded
            su[i] = s;
        } else {
            ws[i * 16 + b] = s;                           // wT[k][j]
            sw[i] = s;
        }
        __syncthreads();
        if (tid < 64) {
            float p = su[tid] * sw[tid];
            #pragma unroll
            for (int m = 32; m >= 1; m >>= 1) p += __shfl_xor(p, m, 64);
            if (tid == 0) ws[2064 + b] = -p * (1.0f / WIDTH);   // nuw[b]
        }
    } else {
        if (tid < WIDTH) {
            const int row = 2 * BS_ + tid;
            float s = b3[row];
            const float4* W3v = (const float4*)(W3 + row * HID);
            #pragma unroll 8
            for (int k = 0; k < HID / 4; ++k) {
                float4 wv = W3v[k];
                s = fmaf(wv.x, h2[4 * k + 0], s);
                s = fmaf(wv.y, h2[4 * k + 1], s);
                s = fmaf(wv.z, h2[4 * k + 2], s);
                s = fmaf(wv.w, h2[4 * k + 3], s);
            }
            ws[2048 + tid] = s;   // bb
        }
    }
}

__global__ __launch_bounds__(NTHREADS, 5) void cnf_main(
    const float* __restrict__ z, const float* __restrict__ ws,
    float* __restrict__ dz, float* __restrict__ dlog, int n)
{
    // Wave-private transpose slices: 4 waves x 64 rows x 8 float4 = 32 KB.
    // ZERO barriers: each wave touches only slice[wv], and same-wave DS ops
    // execute in order in the LDS pipe (validated in round 5).
    // Each half h stages 8 float4/row = one full 128B line per row -> stores
    // cover complete cache lines (round 5's partial-line RMW is avoided).
    __shared__ __align__(16) float4 slice[4][64][8];

    const int tid = threadIdx.x;
    const int wv  = tid >> 6;
    const int l   = tid & 63;
    const int base = blockIdx.x * NTHREADS;
    const int row  = base + tid;
    const bool valid = row < n;
    const int lrow = valid ? row : (n - 1);
    const int wbase = base + wv * 64;

    const float4* zg = (const float4*)z + (size_t)lrow * 16;

    // phase 1: a[j] = bb[j] + sum_k z[k] * wT[k][j]  (weights via uniform s_load)
    float a[WIDTH];
    #pragma unroll
    for (int j = 0; j < WIDTH; ++j) a[j] = ws[2048 + j];

    #pragma unroll
    for (int kc = 0; kc < 16; ++kc) {
        const float4 zv = zg[kc];
        const float* wk = ws + kc * 64;   // wT rows 4kc..4kc+3
        #pragma unroll
        for (int j = 0; j < WIDTH; ++j) a[j] = fmaf(zv.x, wk[j],      a[j]);
        #pragma unroll
        for (int j = 0; j < WIDTH; ++j) a[j] = fmaf(zv.y, wk[16 + j], a[j]);
        #pragma unroll
        for (int j = 0; j < WIDTH; ++j) a[j] = fmaf(zv.z, wk[32 + j], a[j]);
        #pragma unroll
        for (int j = 0; j < WIDTH; ++j) a[j] = fmaf(zv.w, wk[48 + j], a[j]);
    }

    // tanh + trace
    float tr = 0.0f;
    #pragma unroll
    for (int j = 0; j < WIDTH; ++j) {
        float th = fast_tanh(a[j]);
        a[j] = th;
        tr = fmaf(1.0f - th * th, ws[2064 + j], tr);
    }
    if (valid) dlog[row] = tr;

    // phase 2: dz = th @ uT in two 128B halves through the wave-private slice
    const float* uT = ws + 1024;
    float4* dzv = (float4*)dz;

    #pragma unroll
    for (int h = 0; h < 2; ++h) {
        // compute 8 float4 (one full cache line of this thread's row), stash in LDS
        #pragma unroll
        for (int c = 0; c < 8; ++c) {
            const int d0 = h * 32 + c * 4;
            float4 o = make_float4(0.f, 0.f, 0.f, 0.f);
            #pragma unroll
            for (int j = 0; j < WIDTH; ++j) {
                const float th = a[j];
                o.x = fmaf(th, uT[(d0 + 0) * 16 + j], o.x);
                o.y = fmaf(th, uT[(d0 + 1) * 16 + j], o.y);
                o.z = fmaf(th, uT[(d0 + 2) * 16 + j], o.z);
                o.w = fmaf(th, uT[(d0 + 3) * 16 + j], o.w);
            }
            slice[wv][l][c ^ (l & 7)] = o;   // XOR-swizzled: 8 words/bank floor
        }
        // transposed store: 8 instrs, each 8 rows x full 128B line
        #pragma unroll
        for (int s = 0; s < 8; ++s) {
            const int r = 8 * s + (l >> 3);          // row within wave's 64
            const float4 v = slice[wv][r][(l & 7) ^ (l >> 3)];
            const int grow = wbase + r;
            if (grow < n)
                dzv[(size_t)grow * 16 + h * 8 + (l & 7)] = v;
        }
    }
}

extern "C" void kernel_launch(void* const* d_in, const int* in_sizes, int n_in,
                              void* d_out, int out_size, void* d_ws, size_t ws_size,
                              hipStream_t stream) {
    const float* t  = (const float*)d_in[0];
    const float* z  = (const float*)d_in[1];
    const float* W1 = (const float*)d_in[2];
    const float* b1 = (const float*)d_in[3];
    const float* W2 = (const float*)d_in[4];
    const float* b2 = (const float*)d_in[5];
    const float* W3 = (const float*)d_in[6];
    const float* b3 = (const float*)d_in[7];

    const int n = in_sizes[1] / IO_DIM;   // 500000
    float* ws   = (float*)d_ws;
    float* out  = (float*)d_out;
    float* dz   = out;
    float* dlog = out + (size_t)n * IO_DIM;

    cnf_prep<<<17, 128, 0, stream>>>(t, W1, b1, W2, b2, W3, b3, ws);

    const int grid = (n + NTHREADS - 1) / NTHREADS;
    cnf_main<<<grid, NTHREADS, 0, stream>>>(z, ws, dz, dlog, n);
}

// Round 7
// 71.372 us; speedup vs baseline: 1.2606x; 1.1200x over previous
//
#include <hip/hip_runtime.h>

#define IO_DIM 64
#define WIDTH 16
#define HID 128
#define BS_ 1024                 // 64*16
#define NTHREADS 128             // 2 waves/block -> 16 KB LDS/block

// ws layout v2 (floats):
//   wT [64][16]  at    0..1024)   : wT[k][j] = w[j][k]
//   uT [64][16]  at 1024..2048)   : uT[d][j] = u[j][d] / 16
//   bb [16]      at 2048..2064)
//   nuw[16]      at 2064..2080)   : -uw[j] / 16

__device__ __forceinline__ float fast_tanh(float x) {
    float e = __expf(2.0f * x);
    return 1.0f - __fdividef(2.0f, e + 1.0f);
}

__global__ __launch_bounds__(128) void cnf_prep(
    const float* __restrict__ t, const float* __restrict__ W1,
    const float* __restrict__ b1, const float* __restrict__ W2,
    const float* __restrict__ b2, const float* __restrict__ W3,
    const float* __restrict__ b3, float* __restrict__ ws)
{
    __shared__ float h1[HID];
    __shared__ float h2[HID];
    __shared__ float su[64], sw[64];
    const int tid = threadIdx.x;

    h1[tid] = tanhf(W1[tid] * t[0] + b1[tid]);
    __syncthreads();

    {
        float s = b2[tid];
        const float4* W2v = (const float4*)(W2 + tid * HID);
        #pragma unroll 8
        for (int k = 0; k < HID / 4; ++k) {
            float4 wv = W2v[k];
            s = fmaf(wv.x, h1[4 * k + 0], s);
            s = fmaf(wv.y, h1[4 * k + 1], s);
            s = fmaf(wv.z, h1[4 * k + 2], s);
            s = fmaf(wv.w, h1[4 * k + 3], s);
        }
        h2[tid] = tanhf(s);
    }
    __syncthreads();

    const int b = blockIdx.x;
    if (b < 16) {
        // block b owns output row j=b of both u and w (64 elements each)
        const int half = tid >> 6;   // 0 -> u, 1 -> w
        const int i = tid & 63;      // element index (d or k)
        const int row = half * BS_ + b * 64 + i;
        float s = b3[row];
        const float4* W3v = (const float4*)(W3 + row * HID);
        #pragma unroll 8
        for (int k = 0; k < HID / 4; ++k) {
            float4 wv = W3v[k];
            s = fmaf(wv.x, h2[4 * k + 0], s);
            s = fmaf(wv.y, h2[4 * k + 1], s);
            s = fmaf(wv.z, h2[4 * k + 2], s);
            s = fmaf(wv.w, h2[4 * k + 3], s);
        }
        if (half == 0) {
            ws[1024 + i * 16 + b] = s * (1.0f / WIDTH);   // uT[d][j], scale folded
            su[i] = s;
        } else {
            ws[i * 16 + b] = s;                           // wT[k][j]
            sw[i] = s;
        }
        __syncthreads();
        if (tid < 64) {
            float p = su[tid] * sw[tid];
            #pragma unroll
            for (int m = 32; m >= 1; m >>= 1) p += __shfl_xor(p, m, 64);
            if (tid == 0) ws[2064 + b] = -p * (1.0f / WIDTH);   // nuw[b]
        }
    } else {
        if (tid < WIDTH) {
            const int row = 2 * BS_ + tid;
            float s = b3[row];
            const float4* W3v = (const float4*)(W3 + row * HID);
            #pragma unroll 8
            for (int k = 0; k < HID / 4; ++k) {
                float4 wv = W3v[k];
                s = fmaf(wv.x, h2[4 * k + 0], s);
                s = fmaf(wv.y, h2[4 * k + 1], s);
                s = fmaf(wv.z, h2[4 * k + 2], s);
                s = fmaf(wv.w, h2[4 * k + 3], s);
            }
            ws[2048 + tid] = s;   // bb
        }
    }
}

__global__ __launch_bounds__(NTHREADS, 5) void cnf_main(
    const float* __restrict__ z, const float* __restrict__ ws,
    float* __restrict__ dz, float* __restrict__ dlog, int n)
{
    // Wave-private transpose slices: 2 waves x 64 rows x 8 float4 = 16 KB.
    // ZERO barriers: each wave touches only slice[wv]; same-wave DS ops are
    // in-order (validated rounds 5/6). Stores cover full 128B lines
    // (8 lanes x 16B per row, 8 consecutive rows per instruction).
    __shared__ __align__(16) float4 slice[2][64][8];

    const int tid = threadIdx.x;
    const int wv  = tid >> 6;
    const int l   = tid & 63;
    const int base = blockIdx.x * NTHREADS;
    const int row  = base + tid;
    const bool valid = row < n;
    const int lrow = valid ? row : (n - 1);
    const int wbase = base + wv * 64;

    // burst-load own z row (16 outstanding dwordx4, one wait chain)
    const float4* zg = (const float4*)z + (size_t)lrow * 16;
    float4 zr[16];
    #pragma unroll
    for (int i = 0; i < 16; ++i) zr[i] = zg[i];

    // phase 1: a[j] = bb[j] + sum_k z[k] * wT[k][j]  (weights via uniform s_load)
    float a[WIDTH];
    #pragma unroll
    for (int j = 0; j < WIDTH; ++j) a[j] = ws[2048 + j];

    #pragma unroll
    for (int kc = 0; kc < 16; ++kc) {
        const float4 zv = zr[kc];
        const float* wk = ws + kc * 64;   // wT rows 4kc..4kc+3
        #pragma unroll
        for (int j = 0; j < WIDTH; ++j) a[j] = fmaf(zv.x, wk[j],      a[j]);
        #pragma unroll
        for (int j = 0; j < WIDTH; ++j) a[j] = fmaf(zv.y, wk[16 + j], a[j]);
        #pragma unroll
        for (int j = 0; j < WIDTH; ++j) a[j] = fmaf(zv.z, wk[32 + j], a[j]);
        #pragma unroll
        for (int j = 0; j < WIDTH; ++j) a[j] = fmaf(zv.w, wk[48 + j], a[j]);
    }

    // tanh + trace
    float tr = 0.0f;
    #pragma unroll
    for (int j = 0; j < WIDTH; ++j) {
        float th = fast_tanh(a[j]);
        a[j] = th;
        tr = fmaf(1.0f - th * th, ws[2064 + j], tr);
    }
    if (valid) dlog[row] = tr;

    // phase 2: dz = th @ uT in two 128B halves through the wave-private slice
    const float* uT = ws + 1024;
    float4* dzv = (float4*)dz;

    #pragma unroll
    for (int h = 0; h < 2; ++h) {
        // compute 8 float4 (one full cache line of this thread's row) -> LDS
        #pragma unroll
        for (int c = 0; c < 8; ++c) {
            const int d0 = h * 32 + c * 4;
            float4 o = make_float4(0.f, 0.f, 0.f, 0.f);
            #pragma unroll
            for (int j = 0; j < WIDTH; ++j) {
                const float th = a[j];
                o.x = fmaf(th, uT[(d0 + 0) * 16 + j], o.x);
                o.y = fmaf(th, uT[(d0 + 1) * 16 + j], o.y);
                o.z = fmaf(th, uT[(d0 + 2) * 16 + j], o.z);
                o.w = fmaf(th, uT[(d0 + 3) * 16 + j], o.w);
            }
            slice[wv][l][c ^ (l & 7)] = o;   // XOR-swizzled: 8 words/bank floor
        }
        // transposed store: 8 instrs, each 8 consecutive rows x full 128B line
        #pragma unroll
        for (int s = 0; s < 8; ++s) {
            const int r = 8 * s + (l >> 3);          // row within wave's 64
            const float4 v = slice[wv][r][(l & 7) ^ (l >> 3)];
            const int grow = wbase + r;
            if (grow < n)
                dzv[(size_t)grow * 16 + h * 8 + (l & 7)] = v;
        }
    }
}

extern "C" void kernel_launch(void* const* d_in, const int* in_sizes, int n_in,
                              void* d_out, int out_size, void* d_ws, size_t ws_size,
                              hipStream_t stream) {
    const float* t  = (const float*)d_in[0];
    const float* z  = (const float*)d_in[1];
    const float* W1 = (const float*)d_in[2];
    const float* b1 = (const float*)d_in[3];
    const float* W2 = (const float*)d_in[4];
    const float* b2 = (const float*)d_in[5];
    const float* W3 = (const float*)d_in[6];
    const float* b3 = (const float*)d_in[7];

    const int n = in_sizes[1] / IO_DIM;   // 500000
    float* ws   = (float*)d_ws;
    float* out  = (float*)d_out;
    float* dz   = out;
    float* dlog = out + (size_t)n * IO_DIM;

    cnf_prep<<<17, 128, 0, stream>>>(t, W1, b1, W2, b2, W3, b3, ws);

    const int grid = (n + NTHREADS - 1) / NTHREADS;
    cnf_main<<<grid, NTHREADS, 0, stream>>>(z, ws, dz, dlog, n);
}